// Round 1
// baseline (18046.317 us; speedup 1.0000x reference)
//
#include <hip/hip_runtime.h>

// LSTM fused: 2-layer LSTM (B=128,T=512,I=512,H=1024) + final linear (O=512).
// Strategy: per-step fused kernel, layer1 pipelined one step behind layer0.
// gates = [W_ih | W_hh] @ [x_t ; h_prev] as bf16 MFMA GEMM, fp32 accum,
// fp32 cell state. Weight rows permuted prow=4*j+gate so each 32-row block
// holds all 4 gates for 8 hidden units -> block-local LSTM epilogue.

#define B_ 128
#define T_ 512
#define I_ 512
#define H_ 1024
#define O_ 512

typedef __attribute__((ext_vector_type(8))) __bf16 bf16x8;
typedef __attribute__((ext_vector_type(4))) float f32x4;

// ---------------- prep kernels ----------------

__global__ void pack_w_kernel(const float* __restrict__ Wi, const float* __restrict__ Wh,
                              const float* __restrict__ bi, const float* __restrict__ bh,
                              __bf16* __restrict__ Wp, float* __restrict__ bp,
                              int Ki, int Kh) {
    int prow = blockIdx.x;            // 0..4095 permuted row
    int j = prow >> 2, g = prow & 3;  // hidden unit, gate (i,f,g,o)
    int orow = g * H_ + j;            // original row in [4H, K] weight
    int K = Ki + Kh;
    const float* src_i = Wi + (size_t)orow * Ki;
    const float* src_h = Wh + (size_t)orow * Kh;
    __bf16* dst = Wp + (size_t)prow * K;
    for (int c = threadIdx.x; c < K; c += blockDim.x) {
        float v = (c < Ki) ? src_i[c] : src_h[c - Ki];
        dst[c] = (__bf16)v;
    }
    if (threadIdx.x == 0) bp[prow] = bi[orow] + bh[orow];
}

__global__ void pack_lin_kernel(const float* __restrict__ W, __bf16* __restrict__ Wb) {
    size_t i = (size_t)blockIdx.x * 256 + threadIdx.x;  // covers 512*1024
    Wb[i] = (__bf16)W[i];
}

__global__ void xpose_kernel(const float* __restrict__ x, __bf16* __restrict__ xb) {
    int blk = blockIdx.x;           // b*T + t
    int b = blk >> 9, t = blk & (T_ - 1);
    const float* src = x + ((size_t)b * T_ + t) * I_;
    __bf16* dst = xb + ((size_t)t * B_ + b) * I_;
    int c = threadIdx.x * 2;
    float2 v = *(const float2*)(src + c);
    dst[c]     = (__bf16)v.x;
    dst[c + 1] = (__bf16)v.y;
}

__global__ void zero_kernel(float4* __restrict__ p) {
    p[(size_t)blockIdx.x * 256 + threadIdx.x] = make_float4(0.f, 0.f, 0.f, 0.f);
}

// ---------------- fused LSTM step ----------------
// Grid 256 blocks x 256 thr. Blocks 0..127: layer0 step s (if s<512).
// Blocks 128..255: layer1 step s-1 (if s>=1). Block nb computes permuted gate
// rows [32*nb, 32*nb+32) for all 128 batches, then the LSTM pointwise update
// for hidden units [8*nb, 8*nb+8).

__device__ __forceinline__ float sigf(float x) { return 1.f / (1.f + __expf(-x)); }
__device__ __forceinline__ float tanhf_fast(float x) { return 2.f / (1.f + __expf(-2.f * x)) - 1.f; }

__launch_bounds__(256, 2)
__global__ void step_kernel(
    const __bf16* __restrict__ W0p, const __bf16* __restrict__ W1p,
    const float* __restrict__ bias0, const float* __restrict__ bias1,
    const __bf16* __restrict__ xb,
    __bf16* __restrict__ h1buf, __bf16* __restrict__ h2buf,
    float* __restrict__ c0, float* __restrict__ c1,
    __bf16* __restrict__ h2all,
    int s)
{
    const int blk = blockIdx.x;
    const bool l1 = blk >= 128;
    if (!l1 && s >= T_) return;
    if (l1 && s == 0) return;
    const int nb = l1 ? blk - 128 : blk;
    const int t = l1 ? s - 1 : s;

    const __bf16* A0; const __bf16* A1; const __bf16* Wp;
    const float* bias; float* cbuf; __bf16* hout;
    int KS, K, rs0;
    if (!l1) {
        KS = I_; K = I_ + H_; rs0 = I_;
        A0 = xb + (size_t)t * B_ * I_;                       // x_t  [128,512]
        A1 = h1buf + (size_t)((t + 1) & 1) * (B_ * H_);      // h1_{t-1}
        Wp = W0p; bias = bias0; cbuf = c0;
        hout = h1buf + (size_t)(t & 1) * (B_ * H_);
    } else {
        KS = H_; K = 2 * H_; rs0 = H_;
        A0 = h1buf + (size_t)(t & 1) * (B_ * H_);            // h1_t (this launch-1)
        A1 = h2buf + (size_t)((t + 1) & 1) * (B_ * H_);      // h2_{t-1}
        Wp = W1p; bias = bias1; cbuf = c1;
        hout = h2buf + (size_t)(t & 1) * (B_ * H_);
    }

    __shared__ __bf16 As[128][32];
    __shared__ __bf16 Bs[32][32];
    __shared__ float  Gs[4][32][32];

    const int tid = threadIdx.x;
    const int w = tid >> 6, l = tid & 63;

    f32x4 acc00 = {0.f,0.f,0.f,0.f}, acc01 = {0.f,0.f,0.f,0.f};
    f32x4 acc10 = {0.f,0.f,0.f,0.f}, acc11 = {0.f,0.f,0.f,0.f};

    const int arow = tid >> 1;          // 0..127
    const int acol = (tid & 1) * 16;    // 0 / 16
    const int brow = tid >> 3;          // 0..31
    const int bcol = (tid & 7) * 4;     // 0..28
    const __bf16* wrow = Wp + (size_t)(nb * 32 + brow) * K + bcol;

    const int nchunks = K / 32;
    for (int kb = 0; kb < nchunks; ++kb) {
        const int k0 = kb * 32;
        const __bf16* abase = (k0 < KS)
            ? (A0 + (size_t)arow * rs0 + k0 + acol)
            : (A1 + (size_t)arow * H_ + (k0 - KS) + acol);
        __syncthreads();
        *(bf16x8*)&As[arow][acol]     = *(const bf16x8*)abase;
        *(bf16x8*)&As[arow][acol + 8] = *(const bf16x8*)(abase + 8);
        *(uint2*)&Bs[brow][bcol]      = *(const uint2*)(wrow + k0);
        __syncthreads();
        bf16x8 a0 = *(const bf16x8*)&As[w * 32 + (l & 15)][(l >> 4) * 8];
        bf16x8 a1 = *(const bf16x8*)&As[w * 32 + 16 + (l & 15)][(l >> 4) * 8];
        bf16x8 b0 = *(const bf16x8*)&Bs[(l & 15)][(l >> 4) * 8];
        bf16x8 b1 = *(const bf16x8*)&Bs[16 + (l & 15)][(l >> 4) * 8];
        acc00 = __builtin_amdgcn_mfma_f32_16x16x32_bf16(a0, b0, acc00, 0, 0, 0);
        acc01 = __builtin_amdgcn_mfma_f32_16x16x32_bf16(a0, b1, acc01, 0, 0, 0);
        acc10 = __builtin_amdgcn_mfma_f32_16x16x32_bf16(a1, b0, acc10, 0, 0, 0);
        acc11 = __builtin_amdgcn_mfma_f32_16x16x32_bf16(a1, b1, acc11, 0, 0, 0);
    }
    __syncthreads();
    // Dump acc -> Gs: batch_local = mi*16 + (l>>4)*4 + r, prow_local = ni*16 + (l&15)
    {
        const int r0 = (l >> 4) * 4, cA = l & 15;
        for (int r = 0; r < 4; ++r) {
            Gs[w][r0 + r][cA]          = acc00[r];
            Gs[w][r0 + r][16 + cA]     = acc01[r];
            Gs[w][16 + r0 + r][cA]     = acc10[r];
            Gs[w][16 + r0 + r][16 + cA]= acc11[r];
        }
    }
    __syncthreads();
    // Epilogue: 128 batches x 8 hidden units, 4 pairs per thread
    const float* bb = bias + nb * 32;
    for (int p = 0; p < 4; ++p) {
        int idx = p * 256 + tid;       // 0..1023
        int b  = idx >> 3;             // batch
        int ju = idx & 7;              // local hidden unit
        int ww = b >> 5, bl = b & 31;
        float gi = Gs[ww][bl][4 * ju + 0] + bb[4 * ju + 0];
        float gf = Gs[ww][bl][4 * ju + 1] + bb[4 * ju + 1];
        float gg = Gs[ww][bl][4 * ju + 2] + bb[4 * ju + 2];
        float go = Gs[ww][bl][4 * ju + 3] + bb[4 * ju + 3];
        float ig = sigf(gi), fg = sigf(gf), g2 = tanhf_fast(gg), og = sigf(go);
        int j = nb * 8 + ju;
        size_t cidx = (size_t)b * H_ + j;
        float c = fg * cbuf[cidx] + ig * g2;
        cbuf[cidx] = c;
        float h = og * tanhf_fast(c);
        __bf16 hb = (__bf16)h;
        hout[cidx] = hb;
        if (l1) h2all[((size_t)t * B_ + b) * H_ + j] = hb;
    }
}

// ---------------- final linear ----------------
// out[b][t][o] = sum_h h2all[t][b][h] * Wlin[o][h] + blin[o]
// M = T*B = 65536 rows (a = t*128+b), N = 512, K = 1024.

__launch_bounds__(256, 2)
__global__ void final_kernel(const __bf16* __restrict__ h2all,
                             const __bf16* __restrict__ Wlin,
                             const float* __restrict__ blin,
                             float* __restrict__ out)
{
    const int mb = blockIdx.x >> 4;   // 512 tiles of 128 rows
    const int nb = blockIdx.x & 15;   // 16 tiles of 32 cols
    const int tid = threadIdx.x, w = tid >> 6, l = tid & 63;
    __shared__ __bf16 As[128][32];
    __shared__ __bf16 Bs[32][32];
    f32x4 acc00 = {0.f,0.f,0.f,0.f}, acc01 = {0.f,0.f,0.f,0.f};
    f32x4 acc10 = {0.f,0.f,0.f,0.f}, acc11 = {0.f,0.f,0.f,0.f};
    const int arow = tid >> 1, acol = (tid & 1) * 16;
    const int brow = tid >> 3, bcol = (tid & 7) * 4;
    const __bf16* abase = h2all + ((size_t)mb * 128 + arow) * H_ + acol;
    const __bf16* wrow  = Wlin + (size_t)(nb * 32 + brow) * H_ + bcol;
    for (int kb = 0; kb < H_ / 32; ++kb) {
        const int k0 = kb * 32;
        __syncthreads();
        *(bf16x8*)&As[arow][acol]     = *(const bf16x8*)(abase + k0);
        *(bf16x8*)&As[arow][acol + 8] = *(const bf16x8*)(abase + k0 + 8);
        *(uint2*)&Bs[brow][bcol]      = *(const uint2*)(wrow + k0);
        __syncthreads();
        bf16x8 a0 = *(const bf16x8*)&As[w * 32 + (l & 15)][(l >> 4) * 8];
        bf16x8 a1 = *(const bf16x8*)&As[w * 32 + 16 + (l & 15)][(l >> 4) * 8];
        bf16x8 b0 = *(const bf16x8*)&Bs[(l & 15)][(l >> 4) * 8];
        bf16x8 b1 = *(const bf16x8*)&Bs[16 + (l & 15)][(l >> 4) * 8];
        acc00 = __builtin_amdgcn_mfma_f32_16x16x32_bf16(a0, b0, acc00, 0, 0, 0);
        acc01 = __builtin_amdgcn_mfma_f32_16x16x32_bf16(a0, b1, acc01, 0, 0, 0);
        acc10 = __builtin_amdgcn_mfma_f32_16x16x32_bf16(a1, b0, acc10, 0, 0, 0);
        acc11 = __builtin_amdgcn_mfma_f32_16x16x32_bf16(a1, b1, acc11, 0, 0, 0);
    }
    const int r0 = (l >> 4) * 4, cA = l & 15;
    for (int mi = 0; mi < 2; ++mi)
        for (int ni = 0; ni < 2; ++ni) {
            f32x4 acc = (mi == 0) ? (ni == 0 ? acc00 : acc01) : (ni == 0 ? acc10 : acc11);
            for (int r = 0; r < 4; ++r) {
                int a = mb * 128 + w * 32 + mi * 16 + r0 + r;
                int o = nb * 32 + ni * 16 + cA;
                int b = a & 127, t = a >> 7;
                out[(size_t)b * (T_ * O_) + (size_t)t * O_ + o] = acc[r] + blin[o];
            }
        }
}

// ---------------- launch ----------------

extern "C" void kernel_launch(void* const* d_in, const int* in_sizes, int n_in,
                              void* d_out, int out_size, void* d_ws, size_t ws_size,
                              hipStream_t stream) {
    const float* x     = (const float*)d_in[0];
    const float* W_ih0 = (const float*)d_in[1];
    const float* W_hh0 = (const float*)d_in[2];
    const float* b_ih0 = (const float*)d_in[3];
    const float* b_hh0 = (const float*)d_in[4];
    const float* W_ih1 = (const float*)d_in[5];
    const float* W_hh1 = (const float*)d_in[6];
    const float* b_ih1 = (const float*)d_in[7];
    const float* b_hh1 = (const float*)d_in[8];
    const float* W_lin = (const float*)d_in[9];
    const float* b_lin = (const float*)d_in[10];
    float* out = (float*)d_out;

    char* ws = (char*)d_ws;
    __bf16* W0p = (__bf16*)ws;   ws += (size_t)4096 * 1536 * 2;   // 12.6 MB
    __bf16* W1p = (__bf16*)ws;   ws += (size_t)4096 * 2048 * 2;   // 16.8 MB
    __bf16* Wlb = (__bf16*)ws;   ws += (size_t)512 * 1024 * 2;    // 1 MB
    float* bias0 = (float*)ws;   ws += (size_t)4096 * 4;
    float* bias1 = (float*)ws;   ws += (size_t)4096 * 4;
    __bf16* xb   = (__bf16*)ws;  ws += (size_t)T_ * B_ * I_ * 2;  // 67 MB
    __bf16* h2all= (__bf16*)ws;  ws += (size_t)T_ * B_ * H_ * 2;  // 134 MB
    char* zbase = ws;            // contiguous zero region: 2 MB
    __bf16* h1buf = (__bf16*)ws; ws += (size_t)2 * B_ * H_ * 2;
    __bf16* h2buf = (__bf16*)ws; ws += (size_t)2 * B_ * H_ * 2;
    float* c0 = (float*)ws;      ws += (size_t)B_ * H_ * 4;
    float* c1 = (float*)ws;      ws += (size_t)B_ * H_ * 4;

    pack_w_kernel<<<4096, 256, 0, stream>>>(W_ih0, W_hh0, b_ih0, b_hh0, W0p, bias0, I_, H_);
    pack_w_kernel<<<4096, 256, 0, stream>>>(W_ih1, W_hh1, b_ih1, b_hh1, W1p, bias1, H_, H_);
    pack_lin_kernel<<<(512 * 1024) / 256, 256, 0, stream>>>(W_lin, Wlb);
    xpose_kernel<<<B_ * T_, 256, 0, stream>>>(x, xb);
    zero_kernel<<<512, 256, 0, stream>>>((float4*)zbase);   // 512*256*16B = 2 MB

    for (int s = 0; s <= T_; ++s)
        step_kernel<<<256, 256, 0, stream>>>(W0p, W1p, bias0, bias1, xb,
                                             h1buf, h2buf, c0, c1, h2all, s);

    final_kernel<<<512 * 16, 256, 0, stream>>>(h2all, Wlb, b_lin, out);
}

// Round 3
// 13780.862 us; speedup vs baseline: 1.3095x; 1.3095x over previous
//
#include <hip/hip_runtime.h>

// 2-layer LSTM (B=128,T=512,I=512,H=1024) + linear (O=512) on gfx950.
// Persistent cooperative kernel: 256 blocks x 512 thr, 514 iterations,
// custom hierarchical grid barrier. Blocks 0-127 = layer0 (computes h1[s]
// and xg1 partial W_ih1@h1[s-1]); blocks 128-255 = layer1 two steps behind.
// W_hh slice in LDS (64KB, resident); W_ih slices stream from warm L2.
// Coherence: producers store h/xg with sc0 sc1 (write-through to LLC);
// readers plain-load FRESH per-timestep regions (no stale-cache hazard,
// no L2 invalidation anywhere). Cell state in registers for all 512 steps.
// R2 bugfix: xg for layer1 timestep t1 is produced at step t1+1 -> slot
// (t1+1)&3 (was t1&3), and an xg-only layer0 tail pass at s==512 produces
// W_ih1@h1[511] which was previously never computed.

#define B_ 128
#define T_ 512
#define I_ 512
#define H_ 1024
#define O_ 512

typedef __attribute__((ext_vector_type(8))) __bf16 bf16x8;
typedef __attribute__((ext_vector_type(4))) float f32x4;

__device__ __forceinline__ float sigf(float x) { return 1.f / (1.f + __expf(-x)); }
__device__ __forceinline__ float tanh_fast(float x) { return 2.f / (1.f + __expf(-2.f * x)) - 1.f; }

// ---- coherent (LLC-level) memory ops: bypass non-coherent per-XCD L2 ----
__device__ __forceinline__ void st_bf16_coh(__bf16* p, float v) {
    unsigned short u = __builtin_bit_cast(unsigned short, (__bf16)v);
    unsigned int uu = u;
    asm volatile("global_store_short %0, %1, off sc0 sc1" :: "v"(p), "v"(uu) : "memory");
}
__device__ __forceinline__ void st_f32x4_coh(float* p, f32x4 v) {
    asm volatile("global_store_dwordx4 %0, %1, off sc0 sc1" :: "v"(p), "v"(v) : "memory");
}

// ---- hierarchical grid barrier: 32 groups of 8 blocks, generation = round ----
__device__ __forceinline__ void gbar(int* cnt, int* root, int round) {
    asm volatile("s_waitcnt vmcnt(0) lgkmcnt(0)" ::: "memory");
    __syncthreads();
    if (threadIdx.x == 0) {
        int g = blockIdx.x & 31;
        int old = __hip_atomic_fetch_add(&cnt[g * 32], 1, __ATOMIC_RELAXED, __HIP_MEMORY_SCOPE_AGENT);
        if ((old & 7) == 7)
            __hip_atomic_fetch_add(root, 1, __ATOMIC_RELAXED, __HIP_MEMORY_SCOPE_AGENT);
        int target = 32 * (round + 1);
        long guard = 0;
        while (__hip_atomic_load(root, __ATOMIC_RELAXED, __HIP_MEMORY_SCOPE_AGENT) < target) {
            __builtin_amdgcn_s_sleep(2);
            if (++guard > (1L << 28)) break;   // safety valve: wrong > hung
        }
    }
    __syncthreads();
    asm volatile("" ::: "memory");
}

// 4x4 transpose across a lane quad (lanes grouped by bits [1:0]).
// in: lane q holds v[r] = C[row r][col q]; out: lane q holds d[g] = C[row q][col g]
__device__ __forceinline__ f32x4 quad_transpose(f32x4 v, int q) {
    f32x4 b, c2, e, d;
#pragma unroll
    for (int r = 0; r < 4; ++r) b[r] = __shfl_xor(v[r], 1);
#pragma unroll
    for (int r = 0; r < 4; ++r) c2[r] = ((q ^ r) & 1) ? b[r ^ 1] : v[r];
#pragma unroll
    for (int r = 0; r < 4; ++r) e[r] = __shfl_xor(c2[r], 2);
#pragma unroll
    for (int r = 0; r < 4; ++r) d[r] = ((q ^ r) & 2) ? e[r ^ 2] : c2[r];
    return d;
}

// ---------------- prep kernels ----------------

// Weight image for MFMA B-frags: img[nb][c][ns][lane][8] bf16, gate-permuted
// prow = 4*j + gate. element = W[prow = nb*32+ns*16+(l&15)][k = c*32+(l>>4)*8+j]
__global__ void pack_img_kernel(const float* __restrict__ Wsrc, __bf16* __restrict__ img,
                                int C, int Ksrc) {
    int nb = blockIdx.x, c = blockIdx.y;
    int tid = threadIdx.x;              // 256
    int ns = tid >> 7, l = (tid >> 1) & 63, j0 = (tid & 1) * 4;
    int P = nb * 32 + ns * 16 + (l & 15);
    int orow = (P & 3) * H_ + (P >> 2);
    int k = c * 32 + ((l >> 4) * 8) + j0;
    const float* src = Wsrc + (size_t)orow * Ksrc + k;
    __bf16* dst = img + ((((size_t)(nb * C + c) * 2 + ns) * 64 + l) * 8 + j0);
    dst[0] = (__bf16)src[0]; dst[1] = (__bf16)src[1];
    dst[2] = (__bf16)src[2]; dst[3] = (__bf16)src[3];
}

__global__ void pack_bias_kernel(const float* __restrict__ bi, const float* __restrict__ bh,
                                 float* __restrict__ bp) {
    int P = blockIdx.x * 256 + threadIdx.x;   // 0..4095 permuted row
    int orow = (P & 3) * H_ + (P >> 2);
    bp[P] = bi[orow] + bh[orow];
}

__global__ void pack_lin_kernel(const float* __restrict__ W, __bf16* __restrict__ Wb) {
    size_t i = (size_t)blockIdx.x * 256 + threadIdx.x;
    Wb[i] = (__bf16)W[i];
}

__global__ void xpose_kernel(const float* __restrict__ x, __bf16* __restrict__ xb) {
    int blk = blockIdx.x;              // b*T + t
    int b = blk >> 9, t = blk & (T_ - 1);
    const float* src = x + ((size_t)b * T_ + t) * I_;
    __bf16* dst = xb + ((size_t)t * B_ + b) * I_;
    int c = threadIdx.x * 2;
    float2 v = *(const float2*)(src + c);
    dst[c] = (__bf16)v.x;
    dst[c + 1] = (__bf16)v.y;
}

// ---------------- persistent LSTM kernel ----------------
// h1all/h2all: 513 slots of [128][1024] bf16; slot t+1 = h(t), slot 0 = zeros.
// xg1buf: ring of 4 slots [128][4096] f32; xg for t1 lives in slot (t1+1)&3.

__launch_bounds__(512, 2)
__global__ void lstm_persist(
    const __bf16* __restrict__ Whh0img, const __bf16* __restrict__ Wih0s,
    const __bf16* __restrict__ Whh1img, const __bf16* __restrict__ Wih1s,
    const float* __restrict__ bias0p, const float* __restrict__ bias1p,
    const __bf16* __restrict__ xb,
    __bf16* __restrict__ h1all, __bf16* __restrict__ h2all,
    float* __restrict__ xg1buf,
    int* bar_cnt, int* bar_root)
{
    const int blk = blockIdx.x;
    const bool isL1 = blk >= 128;
    const int nb = isL1 ? blk - 128 : blk;
    const int tid = threadIdx.x;
    const int w = tid >> 6, l = tid & 63;
    const int rl = l & 15, kcol = (l >> 4) * 8;
    const int q = l & 3, aIdx = (l >> 2) & 3, rowq = l >> 4;
    const int bRow = 16 * w + rowq * 4 + q;       // after-transpose batch index

    __shared__ __bf16 WL[32 * 1024];              // 64 KB: [c][ns][lane][8]

    // resident W_hh slice -> LDS (once)
    {
        const uint4* src = (const uint4*)((isL1 ? Whh1img : Whh0img) + (size_t)nb * 32768);
        uint4* dst = (uint4*)WL;
        for (int i = tid; i < 4096; i += 512) dst[i] = src[i];
    }
    // bias in registers (after-transpose layout)
    float bias_r[2][4];
    {
        const float* bp = (isL1 ? bias1p : bias0p) + nb * 32;
#pragma unroll
        for (int ns = 0; ns < 2; ++ns)
#pragma unroll
            for (int g = 0; g < 4; ++g)
                bias_r[ns][g] = bp[ns * 16 + aIdx * 4 + g];
    }
    __syncthreads();

    const __bf16* myWih0 = Wih0s + (size_t)nb * 16384 + (size_t)l * 8;  // C=16 image
    const __bf16* myWih1 = Wih1s + (size_t)nb * 32768 + (size_t)l * 8;  // C=32 image
    const __bf16* myWL = WL + l * 8;

    float cst[2] = {0.f, 0.f};

    for (int s = 0; s <= 513; ++s) {
        if (!isL1) {
            if (s < T_) {
                const int t = s;
                f32x4 a0 = {0,0,0,0}, a1 = {0,0,0,0}, a2 = {0,0,0,0}, a3 = {0,0,0,0};
                // phase-x: gates0 += W_ih0 @ x_t   (16 chunks, B streamed, L1-shared)
                const __bf16* Ax = xb + ((size_t)t * B_ + 16 * w + rl) * I_ + kcol;
#pragma unroll 4
                for (int c = 0; c < 16; ++c) {
                    bf16x8 av = *(const bf16x8*)(Ax + c * 32);
                    bf16x8 b0 = *(const bf16x8*)(myWih0 + (c * 2 + 0) * 512);
                    bf16x8 b1 = *(const bf16x8*)(myWih0 + (c * 2 + 1) * 512);
                    a0 = __builtin_amdgcn_mfma_f32_16x16x32_bf16(av, b0, a0, 0, 0, 0);
                    a1 = __builtin_amdgcn_mfma_f32_16x16x32_bf16(av, b1, a1, 0, 0, 0);
                }
                __syncthreads();   // wave re-convergence (L1-cache sharing of W streams)
                // phase-h: gates0 += W_hh0 @ h1[t-1]; xg1 += W_ih1 @ h1[t-1]
                const __bf16* Ah = h1all + ((size_t)t * B_ + 16 * w + rl) * H_ + kcol; // slot t = h1[t-1]
                for (int half = 0; half < 2; ++half) {
#pragma unroll 2
                    for (int c = half * 16; c < half * 16 + 16; ++c) {
                        bf16x8 av = *(const bf16x8*)(Ah + c * 32);
                        bf16x8 b0 = *(const bf16x8*)(myWL + (c * 2 + 0) * 512);
                        bf16x8 b1 = *(const bf16x8*)(myWL + (c * 2 + 1) * 512);
                        bf16x8 s2 = *(const bf16x8*)(myWih1 + (c * 2 + 0) * 512);
                        bf16x8 s3 = *(const bf16x8*)(myWih1 + (c * 2 + 1) * 512);
                        a0 = __builtin_amdgcn_mfma_f32_16x16x32_bf16(av, b0, a0, 0, 0, 0);
                        a1 = __builtin_amdgcn_mfma_f32_16x16x32_bf16(av, b1, a1, 0, 0, 0);
                        a2 = __builtin_amdgcn_mfma_f32_16x16x32_bf16(av, s2, a2, 0, 0, 0);
                        a3 = __builtin_amdgcn_mfma_f32_16x16x32_bf16(av, s3, a3, 0, 0, 0);
                    }
                    if (half == 0) __syncthreads();
                }
                // epilogue: LSTM0 update (wave-local, c in registers)
                f32x4 accs[2] = {a0, a1};
#pragma unroll
                for (int ns = 0; ns < 2; ++ns) {
                    f32x4 g4 = quad_transpose(accs[ns], q);
                    float iv = sigf(g4[0] + bias_r[ns][0]);
                    float fv = sigf(g4[1] + bias_r[ns][1]);
                    float gv = tanh_fast(g4[2] + bias_r[ns][2]);
                    float ov = sigf(g4[3] + bias_r[ns][3]);
                    float cn = fv * cst[ns] + iv * gv;
                    cst[ns] = cn;
                    float hv = ov * tanh_fast(cn);
                    __bf16* hp = h1all + ((size_t)(t + 1) * B_ + bRow) * H_ + (nb * 8 + ns * 4 + aIdx);
                    st_bf16_coh(hp, hv);
                }
                // xg1 partial store: this is W_ih1 @ h1[t-1] = xg for t1 = t-1,
                // stored to slot t&3 = (t1+1)&3 (reader uses (t1+1)&3).
                f32x4 accx[2] = {a2, a3};
#pragma unroll
                for (int ns = 0; ns < 2; ++ns) {
                    f32x4 x4 = quad_transpose(accx[ns], q);
                    float* p = xg1buf + ((size_t)(t & 3) * B_ + bRow) * 4096
                             + nb * 32 + ns * 16 + aIdx * 4;
                    st_f32x4_coh(p, x4);
                }
            } else if (s == T_) {
                // xg-only tail: compute W_ih1 @ h1[511] (A = h1all slot 512),
                // store to slot 512&3 = 0 = (511+1)&3. Consumed at s=513 (t1=511).
                f32x4 a2 = {0,0,0,0}, a3 = {0,0,0,0};
                const __bf16* Ah = h1all + ((size_t)T_ * B_ + 16 * w + rl) * H_ + kcol;
#pragma unroll 4
                for (int c = 0; c < 32; ++c) {
                    bf16x8 av = *(const bf16x8*)(Ah + c * 32);
                    bf16x8 s2 = *(const bf16x8*)(myWih1 + (c * 2 + 0) * 512);
                    bf16x8 s3 = *(const bf16x8*)(myWih1 + (c * 2 + 1) * 512);
                    a2 = __builtin_amdgcn_mfma_f32_16x16x32_bf16(av, s2, a2, 0, 0, 0);
                    a3 = __builtin_amdgcn_mfma_f32_16x16x32_bf16(av, s3, a3, 0, 0, 0);
                }
                f32x4 accx[2] = {a2, a3};
#pragma unroll
                for (int ns = 0; ns < 2; ++ns) {
                    f32x4 x4 = quad_transpose(accx[ns], q);
                    float* p = xg1buf + ((size_t)(T_ & 3) * B_ + bRow) * 4096
                             + nb * 32 + ns * 16 + aIdx * 4;
                    st_f32x4_coh(p, x4);
                }
            }
        } else {
            if (s >= 2) {
                const int t1 = s - 2;
                f32x4 a0 = {0,0,0,0}, a1 = {0,0,0,0};
                const __bf16* Ah = h2all + ((size_t)t1 * B_ + 16 * w + rl) * H_ + kcol; // slot t1 = h2[t1-1]
                for (int half = 0; half < 2; ++half) {
#pragma unroll 2
                    for (int c = half * 16; c < half * 16 + 16; ++c) {
                        bf16x8 av = *(const bf16x8*)(Ah + c * 32);
                        bf16x8 b0 = *(const bf16x8*)(myWL + (c * 2 + 0) * 512);
                        bf16x8 b1 = *(const bf16x8*)(myWL + (c * 2 + 1) * 512);
                        a0 = __builtin_amdgcn_mfma_f32_16x16x32_bf16(av, b0, a0, 0, 0, 0);
                        a1 = __builtin_amdgcn_mfma_f32_16x16x32_bf16(av, b1, a1, 0, 0, 0);
                    }
                    if (half == 0) __syncthreads();
                }
                // fetch xg1 tile for t1: lives in slot (t1+1)&3 (written at step t1+1)
                const float* p0 = xg1buf + ((size_t)((t1 + 1) & 3) * B_ + bRow) * 4096 + nb * 32 + aIdx * 4;
                const float* p1 = p0 + 16;
                f32x4 x0, x1;
                asm volatile("global_load_dwordx4 %0, %2, off sc0 sc1\n\t"
                             "global_load_dwordx4 %1, %3, off sc0 sc1\n\t"
                             "s_waitcnt vmcnt(0)"
                             : "=&v"(x0), "=&v"(x1) : "v"(p0), "v"(p1) : "memory");
                f32x4 accs[2] = {a0, a1};
                f32x4 xgs[2] = {x0, x1};
#pragma unroll
                for (int ns = 0; ns < 2; ++ns) {
                    f32x4 g4 = quad_transpose(accs[ns], q);
                    float iv = sigf(g4[0] + xgs[ns][0] + bias_r[ns][0]);
                    float fv = sigf(g4[1] + xgs[ns][1] + bias_r[ns][1]);
                    float gv = tanh_fast(g4[2] + xgs[ns][2] + bias_r[ns][2]);
                    float ov = sigf(g4[3] + xgs[ns][3] + bias_r[ns][3]);
                    float cn = fv * cst[ns] + iv * gv;
                    cst[ns] = cn;
                    float hv = ov * tanh_fast(cn);
                    __bf16* hp = h2all + ((size_t)(t1 + 1) * B_ + bRow) * H_ + (nb * 8 + ns * 4 + aIdx);
                    st_bf16_coh(hp, hv);
                }
            }
        }
        if (s < 513) gbar(bar_cnt, bar_root, s);
    }
}

// ---------------- final linear ----------------
// out[b][t][o] = sum_h h2[t][b][h] * Wlin[o][h] + blin[o]; h2base = h2all + slot1.

__launch_bounds__(256, 2)
__global__ void final_kernel(const __bf16* __restrict__ h2base,
                             const __bf16* __restrict__ Wlin,
                             const float* __restrict__ blin,
                             float* __restrict__ out)
{
    const int mb = blockIdx.x >> 4;
    const int nb = blockIdx.x & 15;
    const int tid = threadIdx.x, w = tid >> 6, l = tid & 63;
    __shared__ __bf16 As[128][32];
    __shared__ __bf16 Bs[32][32];
    f32x4 acc00 = {0,0,0,0}, acc01 = {0,0,0,0}, acc10 = {0,0,0,0}, acc11 = {0,0,0,0};
    const int arow = tid >> 1, acol = (tid & 1) * 16;
    const int brow = tid >> 3, bcol = (tid & 7) * 4;
    const __bf16* abase = h2base + ((size_t)mb * 128 + arow) * H_ + acol;
    const __bf16* wrow = Wlin + (size_t)(nb * 32 + brow) * H_ + bcol;
    for (int kb = 0; kb < H_ / 32; ++kb) {
        const int k0 = kb * 32;
        __syncthreads();
        *(bf16x8*)&As[arow][acol]     = *(const bf16x8*)(abase + k0);
        *(bf16x8*)&As[arow][acol + 8] = *(const bf16x8*)(abase + k0 + 8);
        *(uint2*)&Bs[brow][bcol]      = *(const uint2*)(wrow + k0);
        __syncthreads();
        bf16x8 a0 = *(const bf16x8*)&As[w * 32 + (l & 15)][(l >> 4) * 8];
        bf16x8 a1 = *(const bf16x8*)&As[w * 32 + 16 + (l & 15)][(l >> 4) * 8];
        bf16x8 b0 = *(const bf16x8*)&Bs[(l & 15)][(l >> 4) * 8];
        bf16x8 b1 = *(const bf16x8*)&Bs[16 + (l & 15)][(l >> 4) * 8];
        acc00 = __builtin_amdgcn_mfma_f32_16x16x32_bf16(a0, b0, acc00, 0, 0, 0);
        acc01 = __builtin_amdgcn_mfma_f32_16x16x32_bf16(a0, b1, acc01, 0, 0, 0);
        acc10 = __builtin_amdgcn_mfma_f32_16x16x32_bf16(a1, b0, acc10, 0, 0, 0);
        acc11 = __builtin_amdgcn_mfma_f32_16x16x32_bf16(a1, b1, acc11, 0, 0, 0);
    }
    const int r0 = (l >> 4) * 4, cA = l & 15;
#pragma unroll
    for (int mi = 0; mi < 2; ++mi)
#pragma unroll
        for (int ni = 0; ni < 2; ++ni) {
            f32x4 acc = (mi == 0) ? (ni == 0 ? acc00 : acc01) : (ni == 0 ? acc10 : acc11);
#pragma unroll
            for (int r = 0; r < 4; ++r) {
                int a = mb * 128 + w * 32 + mi * 16 + r0 + r;
                int o = nb * 32 + ni * 16 + cA;
                int b = a & 127, t = a >> 7;
                out[(size_t)b * (T_ * O_) + (size_t)t * O_ + o] = acc[r] + blin[o];
            }
        }
}

// ---------------- launch ----------------

extern "C" void kernel_launch(void* const* d_in, const int* in_sizes, int n_in,
                              void* d_out, int out_size, void* d_ws, size_t ws_size,
                              hipStream_t stream) {
    const float* x     = (const float*)d_in[0];
    const float* W_ih0 = (const float*)d_in[1];
    const float* W_hh0 = (const float*)d_in[2];
    const float* b_ih0 = (const float*)d_in[3];
    const float* b_hh0 = (const float*)d_in[4];
    const float* W_ih1 = (const float*)d_in[5];
    const float* W_hh1 = (const float*)d_in[6];
    const float* b_ih1 = (const float*)d_in[7];
    const float* b_hh1 = (const float*)d_in[8];
    const float* W_lin = (const float*)d_in[9];
    const float* b_lin = (const float*)d_in[10];
    float* out = (float*)d_out;

    char* ws = (char*)d_ws;
    __bf16* Whh0img = (__bf16*)ws; ws += (size_t)4096 * 1024 * 2;      // 8.4 MB
    __bf16* Wih0s   = (__bf16*)ws; ws += (size_t)4096 * 512 * 2;       // 4.2 MB
    __bf16* Whh1img = (__bf16*)ws; ws += (size_t)4096 * 1024 * 2;      // 8.4 MB
    __bf16* Wih1s   = (__bf16*)ws; ws += (size_t)4096 * 1024 * 2;      // 8.4 MB
    __bf16* Wlb     = (__bf16*)ws; ws += (size_t)512 * 1024 * 2;       // 1 MB
    float* bias0p   = (float*)ws;  ws += (size_t)4096 * 4;
    float* bias1p   = (float*)ws;  ws += (size_t)4096 * 4;
    __bf16* xb      = (__bf16*)ws; ws += (size_t)T_ * B_ * I_ * 2;     // 67 MB
    __bf16* h1all   = (__bf16*)ws; ws += (size_t)(T_ + 1) * B_ * H_ * 2; // 134.5 MB
    __bf16* h2all   = (__bf16*)ws; ws += (size_t)(T_ + 1) * B_ * H_ * 2; // 134.5 MB
    float* xg1buf   = (float*)ws;  ws += (size_t)4 * B_ * 4096 * 4;    // 8.4 MB
    int* bar_cnt    = (int*)ws;    ws += 4096;                          // 32 groups, 128B apart
    int* bar_root   = (int*)ws;    ws += 4096;

    // prep
    pack_img_kernel<<<dim3(128, 32), 256, 0, stream>>>(W_hh0, Whh0img, 32, H_);
    pack_img_kernel<<<dim3(128, 16), 256, 0, stream>>>(W_ih0, Wih0s, 16, I_);
    pack_img_kernel<<<dim3(128, 32), 256, 0, stream>>>(W_hh1, Whh1img, 32, H_);
    pack_img_kernel<<<dim3(128, 32), 256, 0, stream>>>(W_ih1, Wih1s, 32, H_);
    pack_bias_kernel<<<16, 256, 0, stream>>>(b_ih0, b_hh0, bias0p);
    pack_bias_kernel<<<16, 256, 0, stream>>>(b_ih1, b_hh1, bias1p);
    pack_lin_kernel<<<(512 * 1024) / 256, 256, 0, stream>>>(W_lin, Wlb);
    xpose_kernel<<<B_ * T_, 256, 0, stream>>>(x, xb);
    hipMemsetAsync(h1all, 0, (size_t)B_ * H_ * 2, stream);   // slot 0 = h1[-1] = 0
    hipMemsetAsync(h2all, 0, (size_t)B_ * H_ * 2, stream);   // slot 0 = h2[-1] = 0
    hipMemsetAsync(bar_cnt, 0, 8192, stream);                 // counters + root

    // persistent recurrence (cooperative: guarantees co-residency for barrier)
    {
        void* kargs[] = {
            (void*)&Whh0img, (void*)&Wih0s, (void*)&Whh1img, (void*)&Wih1s,
            (void*)&bias0p, (void*)&bias1p, (void*)&xb,
            (void*)&h1all, (void*)&h2all, (void*)&xg1buf,
            (void*)&bar_cnt, (void*)&bar_root
        };
        hipLaunchCooperativeKernel((const void*)lstm_persist, dim3(256), dim3(512),
                                   kargs, 0, stream);
    }

    // final linear: reads h2 slots 1..512
    final_kernel<<<512 * 16, 256, 0, stream>>>(h2all + (size_t)B_ * H_, Wlb, b_lin, out);
}